// Round 1
// baseline (556.423 us; speedup 1.0000x reference)
//
#include <hip/hip_runtime.h>
#include <math.h>

typedef __attribute__((ext_vector_type(8))) short short8;
typedef __attribute__((ext_vector_type(4))) float floatx4;

// fp32 -> bf16, round-to-nearest-even, bit pattern in a short
__device__ __forceinline__ short f2bf(float f) {
  union { float f; unsigned u; } v; v.f = f;
  unsigned r = v.u + 0x7fffu + ((v.u >> 16) & 1u);
  return (short)(r >> 16);
}

__device__ __forceinline__ void load_lds16(const float* g, const float* l) {
  __builtin_amdgcn_global_load_lds(
      (const __attribute__((address_space(1))) unsigned int*)g,
      (__attribute__((address_space(3))) unsigned int*)l, 16, 0, 0);
}

// ---------------------------------------------------------------------------
// Prepack adapt_w (fp32 [256][256], o-major) into bf16 MFMA A-fragment order:
// flat short8 index = (t16*8 + kt)*64 + lane, holding W[t16*16 + (lane&15)]
//                     [kt*32 + (lane>>4)*8 .. +7]
// 5 levels * 8192 short8 each.
// ---------------------------------------------------------------------------
__global__ void prepack_w(const float* __restrict__ w0, const float* __restrict__ w1,
                          const float* __restrict__ w2, const float* __restrict__ w3,
                          const float* __restrict__ w4, short8* __restrict__ wp) {
  int id = blockIdx.x * 256 + threadIdx.x;
  if (id >= 5 * 8192) return;
  int lvl = id >> 13;
  int idx = id & 8191;
  const float* W = (lvl == 0) ? w0 : (lvl == 1) ? w1 : (lvl == 2) ? w2 : (lvl == 3) ? w3 : w4;
  int t16 = idx >> 9;
  int kt  = (idx >> 6) & 7;
  int ln  = idx & 63;
  int m = t16 * 16 + (ln & 15);
  int c = kt * 32 + (ln >> 4) * 8;
  const float* s = W + m * 256 + c;
  short8 v;
#pragma unroll
  for (int j = 0; j < 8; j++) v[j] = f2bf(s[j]);
  wp[id] = v;
}

// ---------------------------------------------------------------------------
// Rasterize gt boxes -> per-level float masks in ws.
// grid = (B=8, 5 levels), block = 256
// ---------------------------------------------------------------------------
__global__ void mask_kernel(const float* __restrict__ gtb, float* __restrict__ mask_base) {
  const int szs[5]  = {128, 64, 32, 16, 8};
  const int strd[5] = {8, 16, 32, 64, 128};
  const int offs[5] = {0, 131072, 163840, 172032, 174080};
  int b = blockIdx.x, lvl = blockIdx.y;
  int hw = szs[lvl];
  int P = hw * hw;
  __shared__ int lx[16], ly[16], rx[16], ry[16], dg[16];
  if (threadIdx.x < 16) {
    int n = threadIdx.x;
    const float* bb = gtb + (b * 16 + n) * 4;
    float inv = 1.0f / (float)strd[lvl];   // pow2 stride -> exact
    int qx1 = (int)floorf(bb[0] * inv);
    int qy1 = (int)floorf(bb[1] * inv);
    int qx2 = (int)floorf(bb[2] * inv);
    int qy2 = (int)floorf(bb[3] * inv);
    int wl = hw - 1;
    int a = min(qx1, wl), c = min(qy1, wl), d = min(qx2, wl), e = min(qy2, wl);
    lx[n] = a; ly[n] = c; rx[n] = d; ry[n] = e;
    dg[n] = (a == d) || (c == e);
  }
  __syncthreads();
  float* mp = mask_base + offs[lvl] + b * P;
  for (int p = threadIdx.x; p < P; p += blockDim.x) {
    int y = p / hw, x = p - y * hw;
    bool any = false;
#pragma unroll
    for (int n = 0; n < 16; n++) {
      bool cov = dg[n] ? (y == ly[n] && x == lx[n])
                       : (y >= ly[n] && y < ry[n] && x >= lx[n] && x < rx[n]);
      any = any || cov;
    }
    mp[p] = any ? 1.0f : 0.0f;
  }
}

// ---------------------------------------------------------------------------
// Fused GEMM (adapted = W @ fs_b) + masked squared-diff reduction.
// Block tile: 128(o) x 128(p), BK=32, K=256. 256 threads = 2x2 waves of 64x64.
// A (W) from prepacked bf16 global (L2-resident), B (fs) staged fp32 in LDS via
// global_load_lds, transposed+converted on fragment read.
// grid = (2 Mtiles, ceil(P/128), B)
// ---------------------------------------------------------------------------
__global__ __launch_bounds__(256, 2) void gemm_loss(
    const float* __restrict__ fs, const float* __restrict__ ft,
    const short8* __restrict__ wp, const float* __restrict__ bias,
    const float* __restrict__ mask, float* __restrict__ sums,
    int P, int level) {
  __shared__ float Bs[32 * 128];
  __shared__ float red[8];
  const int tid  = threadIdx.x;
  const int lane = tid & 63;
  const int wave = tid >> 6;
  const int wm = wave & 1, wn = wave >> 1;
  const int quad = lane >> 4, l15 = lane & 15;
  const int bx = blockIdx.x;
  const int p0 = blockIdx.y * 128;
  const int bz = blockIdx.z;

  floatx4 acc[4][4];
#pragma unroll
  for (int i = 0; i < 4; i++)
#pragma unroll
    for (int j = 0; j < 4; j++) acc[i][j] = (floatx4){0.f, 0.f, 0.f, 0.f};

  for (int kt = 0; kt < 8; ++kt) {
    // ---- stage Bs (fp32 [32 c][128 p]) via async global->LDS, 16B/lane ----
#pragma unroll
    for (int qq = 0; qq < 4; ++qq) {
      int F = wave * 1024 + qq * 256 + lane * 4;   // flat fp32 index into Bs
      int c = F >> 7;
      int p = F & 127;
      int pp = p0 + p;
      if (pp > P - 4) pp = P - 4;                  // level-4 (P=64) clamp; junk cols masked later
      const float* g = fs + (size_t)(bz * 256 + kt * 32 + c) * P + pp;
      const float* l = &Bs[wave * 1024 + qq * 256];
      load_lds16(g, l);
    }
    __syncthreads();   // drains vmcnt before barrier (compiler-inserted)

    // ---- A fragments straight from prepacked global (bf16) ----
    short8 af[4];
#pragma unroll
    for (int mi = 0; mi < 4; mi++) {
      int t16 = bx * 8 + wm * 4 + mi;
      af[mi] = wp[(t16 * 8 + kt) * 64 + lane];
    }
    // ---- B fragments: transpose-on-read from LDS + cvt to bf16 ----
    short8 bf[4];
#pragma unroll
    for (int ni = 0; ni < 4; ni++) {
      int n = wn * 64 + ni * 16 + l15;
      short8 t;
#pragma unroll
      for (int j = 0; j < 8; j++) t[j] = f2bf(Bs[(quad * 8 + j) * 128 + n]);
      bf[ni] = t;
    }
#pragma unroll
    for (int mi = 0; mi < 4; mi++)
#pragma unroll
      for (int ni = 0; ni < 4; ni++)
        acc[mi][ni] = __builtin_amdgcn_mfma_f32_16x16x32_bf16(af[mi], bf[ni], acc[mi][ni], 0, 0, 0);
    __syncthreads();   // Bs reuse fence
  }

  // ---- epilogue: diff^2 vs feat_t, masked accumulate ----
  float sgt = 0.f, sbg = 0.f;
#pragma unroll
  for (int ni = 0; ni < 4; ni++) {
    int p = p0 + wn * 64 + ni * 16 + l15;
    bool pv = (p < P);
    float mk = pv ? mask[(size_t)bz * P + p] : 0.f;
#pragma unroll
    for (int mi = 0; mi < 4; mi++) {
      int ob = bx * 128 + wm * 64 + mi * 16 + quad * 4;
#pragma unroll
      for (int r = 0; r < 4; r++) {
        int o = ob + r;
        float ad = acc[mi][ni][r] + bias[o];
        float tv = pv ? ft[(size_t)(bz * 256 + o) * P + p] : ad;  // invalid cols -> diff 0
        float d = tv - ad;
        float sq = d * d;
        sgt += sq * mk;
        sbg += sq * (1.f - mk);
      }
    }
  }
#pragma unroll
  for (int off = 32; off > 0; off >>= 1) {
    sgt += __shfl_down(sgt, off);
    sbg += __shfl_down(sbg, off);
  }
  if (lane == 0) { red[wave * 2] = sgt; red[wave * 2 + 1] = sbg; }
  __syncthreads();
  if (tid == 0) {
    float a = red[0] + red[2] + red[4] + red[6];
    float b = red[1] + red[3] + red[5] + red[7];
    atomicAdd(&sums[level * 2 + 0], a);
    atomicAdd(&sums[level * 2 + 1], b);
  }
}

__global__ void finalize(const float* __restrict__ sums, float* __restrict__ out) {
  if (threadIdx.x == 0 && blockIdx.x == 0) {
    float L = 0.f;
#pragma unroll
    for (int i = 0; i < 5; i++)
      L += 0.004f * sqrtf(sums[2 * i] + 1e-8f) + 0.0002f * sqrtf(sums[2 * i + 1] + 1e-8f);
    out[0] = L;
  }
}

extern "C" void kernel_launch(void* const* d_in, const int* in_sizes, int n_in,
                              void* d_out, int out_size, void* d_ws, size_t ws_size,
                              hipStream_t stream) {
  (void)in_sizes; (void)n_in; (void)out_size; (void)ws_size;
  const float* fs[5]; const float* ftp[5]; const float* aw[5]; const float* ab[5];
  for (int i = 0; i < 5; i++) {
    fs[i]  = (const float*)d_in[4 * i + 0];
    ftp[i] = (const float*)d_in[4 * i + 1];
    aw[i]  = (const float*)d_in[4 * i + 2];
    ab[i]  = (const float*)d_in[4 * i + 3];
  }
  const float* gtb = (const float*)d_in[20];
  float* out = (float*)d_out;
  char* ws = (char*)d_ws;

  float*  sums  = (float*)ws;                    // 16 floats (10 used)
  float*  masks = (float*)(ws + 64);             // 174592 floats
  short8* wp    = (short8*)(ws + 64 + 698368);   // 5 * 8192 short8, 16B aligned

  hipMemsetAsync(sums, 0, 64, stream);
  prepack_w<<<160, 256, 0, stream>>>(aw[0], aw[1], aw[2], aw[3], aw[4], wp);
  mask_kernel<<<dim3(8, 5), 256, 0, stream>>>(gtb, masks);

  const int Ps[5]   = {16384, 4096, 1024, 256, 64};
  const int moff[5] = {0, 131072, 163840, 172032, 174080};
  for (int l = 0; l < 5; l++) {
    int nt = (Ps[l] + 127) / 128;
    gemm_loss<<<dim3(2, nt, 8), 256, 0, stream>>>(
        fs[l], ftp[l], wp + l * 8192, ab[l], masks + moff[l], sums, Ps[l], l);
  }
  finalize<<<1, 64, 0, stream>>>(sums, out);
}

// Round 2
// 454.520 us; speedup vs baseline: 1.2242x; 1.2242x over previous
//
#include <hip/hip_runtime.h>
#include <math.h>

typedef __attribute__((ext_vector_type(8))) short short8;
typedef __attribute__((ext_vector_type(4))) float floatx4;

// fp32 -> bf16, round-to-nearest-even, bit pattern in a short
__device__ __forceinline__ short f2bf(float f) {
  union { float f; unsigned u; } v; v.f = f;
  unsigned r = v.u + 0x7fffu + ((v.u >> 16) & 1u);
  return (short)(r >> 16);
}

struct Params {
  const float* fs[5];
  const float* ft[5];
  const float* bias[5];
  const float* mask[5];
  const short8* wp[5];
  float* sums;
};

// ---------------------------------------------------------------------------
// Prepack adapt_w (fp32 [256][256], o-major) into bf16 MFMA A-fragment order:
// flat short8 index = (t16*8 + kt)*64 + lane, holding W[t16*16 + (lane&15)]
//                     [kt*32 + (lane>>4)*8 .. +7]
// ---------------------------------------------------------------------------
__global__ void prepack_w(const float* __restrict__ w0, const float* __restrict__ w1,
                          const float* __restrict__ w2, const float* __restrict__ w3,
                          const float* __restrict__ w4, short8* __restrict__ wp) {
  int id = blockIdx.x * 256 + threadIdx.x;
  if (id >= 5 * 8192) return;
  int lvl = id >> 13;
  int idx = id & 8191;
  const float* W = (lvl == 0) ? w0 : (lvl == 1) ? w1 : (lvl == 2) ? w2 : (lvl == 3) ? w3 : w4;
  int t16 = idx >> 9;
  int kt  = (idx >> 6) & 7;
  int ln  = idx & 63;
  int m = t16 * 16 + (ln & 15);
  int c = kt * 32 + (ln >> 4) * 8;
  const float* s = W + m * 256 + c;
  short8 v;
#pragma unroll
  for (int j = 0; j < 8; j++) v[j] = f2bf(s[j]);
  wp[id] = v;
}

// ---------------------------------------------------------------------------
// Rasterize gt boxes -> per-level float masks in ws. grid=(8,5), block=256
// ---------------------------------------------------------------------------
__global__ void mask_kernel(const float* __restrict__ gtb, float* __restrict__ mask_base) {
  const int szs[5]  = {128, 64, 32, 16, 8};
  const int strd[5] = {8, 16, 32, 64, 128};
  const int offs[5] = {0, 131072, 163840, 172032, 174080};
  int b = blockIdx.x, lvl = blockIdx.y;
  int hw = szs[lvl];
  int P = hw * hw;
  __shared__ int lx[16], ly[16], rx[16], ry[16], dg[16];
  if (threadIdx.x < 16) {
    int n = threadIdx.x;
    const float* bb = gtb + (b * 16 + n) * 4;
    float inv = 1.0f / (float)strd[lvl];   // pow2 stride -> exact
    int qx1 = (int)floorf(bb[0] * inv);
    int qy1 = (int)floorf(bb[1] * inv);
    int qx2 = (int)floorf(bb[2] * inv);
    int qy2 = (int)floorf(bb[3] * inv);
    int wl = hw - 1;
    int a = min(qx1, wl), c = min(qy1, wl), d = min(qx2, wl), e = min(qy2, wl);
    lx[n] = a; ly[n] = c; rx[n] = d; ry[n] = e;
    dg[n] = (a == d) || (c == e);
  }
  __syncthreads();
  float* mp = mask_base + offs[lvl] + b * P;
  for (int p = threadIdx.x; p < P; p += blockDim.x) {
    int y = p / hw, x = p - y * hw;
    bool any = false;
#pragma unroll
    for (int n = 0; n < 16; n++) {
      bool cov = dg[n] ? (y == ly[n] && x == lx[n])
                       : (y >= ly[n] && y < ry[n] && x >= lx[n] && x < rx[n]);
      any = any || cov;
    }
    mp[p] = any ? 1.0f : 0.0f;
  }
}

// ---------------------------------------------------------------------------
// Fused GEMM + masked loss, all levels in one dispatch, NO LDS staging, NO
// barriers in the K-loop. Block = 256 threads = 4 waves; block tile
// 256(o) x 64(p): wave w owns o in [64w,64w+64), all waves share the same
// 64 p (intra-block fs re-reads hit L1). B-fragments gathered directly from
// global (8 strided dwords per frag) + in-register bf16 cvt -> the compiler
// can keep ~36 loads in flight per wave and interleave with MFMA (no
// vmcnt(0) barrier drain anywhere).
// ---------------------------------------------------------------------------
template<int PL2, int LVL>
__device__ __forceinline__ void level_body(const Params& pr, int rem, float* red) {
  constexpr int P = 64 << PL2;
  const int tid  = threadIdx.x;
  const int lane = tid & 63;
  const int wave = tid >> 6;
  const int quad = lane >> 4, l15 = lane & 15;
  const int bz = rem >> PL2;
  const int p0 = (rem & ((1 << PL2) - 1)) << 6;

  const float*  fsb   = pr.fs[LVL]  + (size_t)bz * 256 * P;
  const float*  ftb   = pr.ft[LVL]  + (size_t)bz * 256 * P;
  const short8* wpb   = pr.wp[LVL]  + (size_t)wave * 4 * 8 * 64;  // t16 = wave*4+mi
  const float*  maskb = pr.mask[LVL] + (size_t)bz * P;
  const float*  biasp = pr.bias[LVL];

  floatx4 acc[4][4];
#pragma unroll
  for (int i = 0; i < 4; i++)
#pragma unroll
    for (int j = 0; j < 4; j++) acc[i][j] = (floatx4){0.f, 0.f, 0.f, 0.f};

#pragma unroll 2
  for (int kt = 0; kt < 8; ++kt) {
    short8 af[4];
#pragma unroll
    for (int mi = 0; mi < 4; mi++)
      af[mi] = wpb[(mi * 8 + kt) * 64 + lane];

    short8 bf[4];
#pragma unroll
    for (int ni = 0; ni < 4; ni++) {
      const float* src = fsb + (size_t)(kt * 32 + quad * 8) * P + (p0 + ni * 16 + l15);
      float t[8];
#pragma unroll
      for (int j = 0; j < 8; j++) t[j] = src[(size_t)j * P];
      short8 v;
#pragma unroll
      for (int j = 0; j < 8; j++) v[j] = f2bf(t[j]);
      bf[ni] = v;
    }
#pragma unroll
    for (int mi = 0; mi < 4; mi++)
#pragma unroll
      for (int ni = 0; ni < 4; ni++)
        acc[mi][ni] = __builtin_amdgcn_mfma_f32_16x16x32_bf16(af[mi], bf[ni], acc[mi][ni], 0, 0, 0);
  }

  // ---- epilogue: diff^2 vs feat_t, masked accumulate ----
  float sgt = 0.f, sbg = 0.f;
#pragma unroll
  for (int ni = 0; ni < 4; ni++) {
    int p = p0 + ni * 16 + l15;
    float mk = maskb[p];
#pragma unroll
    for (int mi = 0; mi < 4; mi++) {
      int ob = wave * 64 + mi * 16 + quad * 4;
      const float* ftp = ftb + (size_t)ob * P + p;
#pragma unroll
      for (int r = 0; r < 4; r++) {
        float ad = acc[mi][ni][r] + biasp[ob + r];
        float tv = ftp[(size_t)r * P];
        float d = tv - ad;
        float sq = d * d;
        sgt += sq * mk;
        sbg += sq - sq * mk;
      }
    }
  }
#pragma unroll
  for (int off = 32; off > 0; off >>= 1) {
    sgt += __shfl_down(sgt, off);
    sbg += __shfl_down(sbg, off);
  }
  if (lane == 0) { red[wave * 2] = sgt; red[wave * 2 + 1] = sbg; }
  __syncthreads();
  if (tid == 0) {
    atomicAdd(&pr.sums[LVL * 2 + 0], red[0] + red[2] + red[4] + red[6]);
    atomicAdd(&pr.sums[LVL * 2 + 1], red[1] + red[3] + red[5] + red[7]);
  }
}

// block-id ranges (x8 batch, p-tiles of 64): L0 [0,2048) L1 [2048,2560)
// L2 [2560,2688) L3 [2688,2720) L4 [2720,2728)
__global__ __launch_bounds__(256, 2) void gemm_loss_all(Params pr) {
  __shared__ float red[8];
  int id = blockIdx.x;
  if (id < 2048)      level_body<8, 0>(pr, id,        red);
  else if (id < 2560) level_body<6, 1>(pr, id - 2048, red);
  else if (id < 2688) level_body<4, 2>(pr, id - 2560, red);
  else if (id < 2720) level_body<2, 3>(pr, id - 2688, red);
  else                level_body<0, 4>(pr, id - 2720, red);
}

__global__ void finalize(const float* __restrict__ sums, float* __restrict__ out) {
  if (threadIdx.x == 0 && blockIdx.x == 0) {
    float L = 0.f;
#pragma unroll
    for (int i = 0; i < 5; i++)
      L += 0.004f * sqrtf(sums[2 * i] + 1e-8f) + 0.0002f * sqrtf(sums[2 * i + 1] + 1e-8f);
    out[0] = L;
  }
}

extern "C" void kernel_launch(void* const* d_in, const int* in_sizes, int n_in,
                              void* d_out, int out_size, void* d_ws, size_t ws_size,
                              hipStream_t stream) {
  (void)in_sizes; (void)n_in; (void)out_size; (void)ws_size;
  const float* fs[5]; const float* ftp[5]; const float* aw[5]; const float* ab[5];
  for (int i = 0; i < 5; i++) {
    fs[i]  = (const float*)d_in[4 * i + 0];
    ftp[i] = (const float*)d_in[4 * i + 1];
    aw[i]  = (const float*)d_in[4 * i + 2];
    ab[i]  = (const float*)d_in[4 * i + 3];
  }
  const float* gtb = (const float*)d_in[20];
  float* out = (float*)d_out;
  char* ws = (char*)d_ws;

  float*  sums  = (float*)ws;                    // 16 floats (10 used)
  float*  masks = (float*)(ws + 64);             // 174592 floats
  short8* wp    = (short8*)(ws + 64 + 698368);   // 5 * 8192 short8, 16B aligned

  hipMemsetAsync(sums, 0, 64, stream);
  prepack_w<<<160, 256, 0, stream>>>(aw[0], aw[1], aw[2], aw[3], aw[4], wp);
  mask_kernel<<<dim3(8, 5), 256, 0, stream>>>(gtb, masks);

  const int moff[5] = {0, 131072, 163840, 172032, 174080};
  Params pr;
  for (int l = 0; l < 5; l++) {
    pr.fs[l]   = fs[l];
    pr.ft[l]   = ftp[l];
    pr.bias[l] = ab[l];
    pr.mask[l] = masks + moff[l];
    pr.wp[l]   = wp + l * 8192;
  }
  pr.sums = sums;

  gemm_loss_all<<<2728, 256, 0, stream>>>(pr);
  finalize<<<1, 64, 0, stream>>>(sums, out);
}